// Round 13
// baseline (231.196 us; speedup 1.0000x reference)
//
#include <hip/hip_runtime.h>
#include <math.h>

#define B_  8
#define E_  1024
#define D_  256
#define H_  16
#define FF_ 1024
#define M_  (B_ * E_)   // 8192 rows

typedef __attribute__((ext_vector_type(8))) short short8;
typedef __attribute__((ext_vector_type(4))) float f32x4;
typedef unsigned short bf16u;

#define GLOAD_LDS16(g, l) __builtin_amdgcn_global_load_lds( \
    (const __attribute__((address_space(1))) void*)(g), \
    (__attribute__((address_space(3))) void*)(l), 16, 0, 0)

__device__ __forceinline__ unsigned short f2bf(float f) {
  union { float f; unsigned u; } c; c.f = f;
  unsigned r = c.u + 0x7fffu + ((c.u >> 16) & 1u);   // RNE
  return (unsigned short)(r >> 16);
}
__device__ __forceinline__ float gelu_exact(float x) {
  return 0.5f * x * (1.0f + erff(x * 0.70710678118654752f));
}

// ---------------------------------------------------------------------------
// bf16 MFMA GEMM — single-barrier double-buffered pipeline (attn-proven
// schedule applied to the GEMM k-loop). Per iter: issue gload_lds(buf^1,k+1)
// -> compute(buf) -> barrier. The barrier's forced vmcnt(0) drain lands
// AFTER a compute phase, hiding the global->LDS latency that the old
// 2-barrier loop exposed 4x per block at K=256. Race-safe with one barrier:
// all waves past barrier(ki) => done reading buf^1 before ki+1 overwrites.
// 64x64 tiles: dbuf LDS = 32KB -> 2 blocks/CU on the measured 64KB pool.
// EPI: 0 = bf16 out (+bias); 1 = f32 out (+bias+R residual); 2 = bf16 gelu;
//      3 = bf16 out (+bias), permuted store qkv[b][head][type][e][16].
// ---------------------------------------------------------------------------
template<int BM, int BN, int EPI>
__global__ __launch_bounds__(256) void mm_k(
    const bf16u* __restrict__ A, const bf16u* __restrict__ Wt,
    const float* __restrict__ bias, const float* __restrict__ R,
    void* __restrict__ Cout, int M, int N, int K)
{
  constexpr int WM = BM / 2, WN = BN / 2;
  constexpr int MT = WM / 16, NT = WN / 16;
  constexpr int PA = BM * 8 / 256, PB = BN * 8 / 256;
  constexpr int LBM = (BM == 128 ? 7 : 6), LBN = (BN == 128 ? 7 : 6);
  __shared__ bf16u As[2][BM * 64];
  __shared__ bf16u Bs[2][BN * 64];

  const int t = threadIdx.x;
  const int l15 = t & 15, quad = (t >> 4) & 3;
  const int w = t >> 6, wm = w >> 1, wn = w & 1;
  const int m0 = blockIdx.x * BM, n0 = blockIdx.y * BN;

  f32x4 acc[MT][NT];
  const f32x4 z4 = {0.f, 0.f, 0.f, 0.f};
#pragma unroll
  for (int i = 0; i < MT; ++i)
#pragma unroll
    for (int j = 0; j < NT; ++j) acc[i][j] = z4;

  const int NK = K >> 6;

  // prologue: stage k-step 0 into buffer 0
#pragma unroll
  for (int p = 0; p < PA; ++p) {
    int g = p * 256 + t;
    int m = g & (BM - 1), c = g >> LBM;
    GLOAD_LDS16(A + (size_t)(m0 + m) * K + c * 8, &As[0][g * 8]);
  }
#pragma unroll
  for (int p = 0; p < PB; ++p) {
    int g = p * 256 + t;
    int n = g & (BN - 1), c = g >> LBN;
    GLOAD_LDS16(Wt + (size_t)(n0 + n) * K + c * 8, &Bs[0][g * 8]);
  }
  __syncthreads();   // k0 staged (vmcnt drained by barrier)

  for (int ki = 0; ki < NK; ++ki) {
    const int cur = ki & 1;

    // issue k+1 loads into buf^1: they land during compute, drained at the
    // end-of-iter barrier (latency hidden instead of exposed)
    if (ki + 1 < NK) {
      const int k0 = (ki + 1) << 6;
#pragma unroll
      for (int p = 0; p < PA; ++p) {
        int g = p * 256 + t;
        int m = g & (BM - 1), c = g >> LBM;
        GLOAD_LDS16(A + (size_t)(m0 + m) * K + k0 + c * 8, &As[cur ^ 1][g * 8]);
      }
#pragma unroll
      for (int p = 0; p < PB; ++p) {
        int g = p * 256 + t;
        int n = g & (BN - 1), c = g >> LBN;
        GLOAD_LDS16(Wt + (size_t)(n0 + n) * K + k0 + c * 8, &Bs[cur ^ 1][g * 8]);
      }
    }

    // compute current buffer
#pragma unroll
    for (int s = 0; s < 2; ++s) {
      short8 af[MT], bfr[NT];
#pragma unroll
      for (int mt = 0; mt < MT; ++mt)
        af[mt] = *(const short8*)(&As[cur][((s * 4 + quad) * BM + wm * WM + mt * 16 + l15) * 8]);
#pragma unroll
      for (int nt = 0; nt < NT; ++nt)
        bfr[nt] = *(const short8*)(&Bs[cur][((s * 4 + quad) * BN + wn * WN + nt * 16 + l15) * 8]);
#pragma unroll
      for (int mt = 0; mt < MT; ++mt)
#pragma unroll
        for (int nt = 0; nt < NT; ++nt)
          acc[mt][nt] = __builtin_amdgcn_mfma_f32_16x16x32_bf16(
              af[mt], bfr[nt], acc[mt][nt], 0, 0, 0);
    }

    __syncthreads();   // buf^1 staged & visible; all waves done with cur
  }

#pragma unroll
  for (int mt = 0; mt < MT; ++mt) {
#pragma unroll
    for (int nt = 0; nt < NT; ++nt) {
      int col = n0 + wn * WN + nt * 16 + l15;
      float bia = bias[col];
#pragma unroll
      for (int r = 0; r < 4; ++r) {
        int row = m0 + wm * WM + mt * 16 + quad * 4 + r;
        float v = acc[mt][nt][r] + bia;
        if (EPI == 3) {
          size_t pidx = ((((size_t)(row >> 10) * 16 + ((col >> 4) & 15)) * 3 +
                          (col >> 8)) * E_ + (row & 1023)) * 16 + (col & 15);
          ((bf16u*)Cout)[pidx] = f2bf(v);
        } else {
          size_t idx = (size_t)row * N + col;
          if (EPI == 1)      { ((float*)Cout)[idx] = v + R[idx]; }
          else if (EPI == 2) { ((bf16u*)Cout)[idx] = f2bf(gelu_exact(v)); }
          else               { ((bf16u*)Cout)[idx] = f2bf(v); }
        }
      }
    }
  }
}

// ---------------------------------------------------------------------------
// Fused prep: weight transposes + bias concat + x conversion, 1 launch.
// ---------------------------------------------------------------------------
__global__ __launch_bounds__(256) void prep_k(
    const float* __restrict__ Wq, const float* __restrict__ Wk,
    const float* __restrict__ Wv, const float* __restrict__ Wo,
    const float* __restrict__ Wf1, const float* __restrict__ Wf2,
    bf16u* __restrict__ Wqkvt, bf16u* __restrict__ Wot,
    bf16u* __restrict__ Wf1t, bf16u* __restrict__ Wf2t,
    const float* __restrict__ bq, const float* __restrict__ bk,
    const float* __restrict__ bv, float* __restrict__ bqkv,
    const float* __restrict__ X, bf16u* __restrict__ Xb)
{
  __shared__ float tile[32][33];
  const int gid = blockIdx.x;
  const int t = threadIdx.x;

  if (gid < 768) {
    const float* src; bf16u* dst; int K, N, bx, by;
    if (gid < 256) {
      const int z = gid >> 6, r = gid & 63;
      src = (z == 0) ? Wq : (z == 1) ? Wk : (z == 2) ? Wv : Wo;
      dst = (z == 0) ? Wqkvt : (z == 1) ? Wqkvt + 65536
          : (z == 2) ? Wqkvt + 131072 : Wot;
      K = 256; N = 256; bx = r & 7; by = r >> 3;
    } else if (gid < 512) {
      const int r = gid - 256;
      src = Wf1; dst = Wf1t; K = 256; N = 1024; bx = r & 7; by = r >> 3;
    } else {
      const int r = gid - 512;
      src = Wf2; dst = Wf2t; K = 1024; N = 256; bx = r & 31; by = r >> 5;
    }
    const int tx = t & 31, ty = t >> 5;
    const int kb = bx * 32, nb = by * 32;
#pragma unroll
    for (int r = 0; r < 4; ++r)
      tile[ty + 8 * r][tx] = src[(size_t)(kb + ty + 8 * r) * N + nb + tx];
    __syncthreads();
#pragma unroll
    for (int r = 0; r < 4; ++r)
      dst[(size_t)(nb + ty + 8 * r) * K + kb + tx] = f2bf(tile[tx][ty + 8 * r]);
  } else if (gid < 771) {
    int i = (gid - 768) * 256 + t;
    bqkv[i] = (i < 256) ? bq[i] : (i < 512) ? bk[i - 256] : bv[i - 512];
  } else {
    int i = (gid - 771) * 256 + t;
    float4 a = ((const float4*)X)[i * 2];
    float4 b = ((const float4*)X)[i * 2 + 1];
    uint4 o;
    o.x = f2bf(a.x) | ((unsigned)f2bf(a.y) << 16);
    o.y = f2bf(a.z) | ((unsigned)f2bf(a.w) << 16);
    o.z = f2bf(b.x) | ((unsigned)f2bf(b.y) << 16);
    o.w = f2bf(b.z) | ((unsigned)f2bf(b.w) << 16);
    ((uint4*)Xb)[i] = o;
  }
}

// ---------------------------------------------------------------------------
// MFMA flash attention — R12 best-measured version, byte-identical
// (55.4-56 us: R9 coalesced-qkv pipeline + setprio T5).
// ---------------------------------------------------------------------------
__global__ __launch_bounds__(256) void attn_k(
    const bf16u* __restrict__ qkv, const int* __restrict__ sb,
    const unsigned char* __restrict__ mask, const float* __restrict__ be,
    bf16u* __restrict__ O)
{
  __shared__ bf16u Kl[2][2][64][40];     // [buf][hp][key][d0-15,mask@16,0@17-31,pad]
  __shared__ bf16u Vt[2][2][2][16][40];  // [buf][hp][s2][d][32 permuted slots+pad]
  __shared__ float emb2[6][2];           // [s][hp] pre-scaled by log2e

  const int t    = threadIdx.x;
  const int b    = blockIdx.z;
  const int hg   = blockIdx.y;          // head pair 0..7
  const int w    = t >> 6;
  const int lane = t & 63;
  const int l15  = lane & 15;
  const int quad = lane >> 4;
  const int q0w  = blockIdx.x * 64 + w * 16;
  const float C2 = 0.36067376022224085f;   // 0.25 * log2(e)

  if (t < 12) emb2[t >> 1][t & 1] = be[(t >> 1) * 16 + hg * 2 + (t & 1)] * 1.44269504088896f;

  {  // zero both Kl buffers: cols 17..31 must stay 0 for the padded MFMA
    float4 z = {0.f, 0.f, 0.f, 0.f};
    float4* kp = (float4*)&Kl[0][0][0][0];
    for (int i = t; i < 1280; i += 256) kp[i] = z;
  }

  // Q B-frag: lane l15 = q, elems = d (quad*8+j); quads 2,3 zero-pad except
  // d=16 (quad2,j0) = 1.0 for the mask-inject trick.
  short8 qf[2];
#pragma unroll
  for (int hp = 0; hp < 2; ++hp) {
    uint4 v = {0u, 0u, 0u, 0u};
    if (quad < 2)
      v = *(const uint4*)(qkv +
          ((((size_t)b * 16 + hg * 2 + hp) * 3 + 0) * E_ + q0w + l15) * 16 + quad * 8);
    else if (quad == 2)
      v.x = 0x3F80u;  // bf16 1.0 (mask-inject slot d=16)
    union { uint4 u; short8 s; } c; c.u = v;
    qf[hp] = c.s;
  }

  // staging roles
  const int s_hp   = t >> 7;         // K/V: which head
  const int s_key  = (t >> 1) & 63;  // K: key
  const int s_half = t & 1;          // K: d-half
  const int vu     = t & 127;
  const int vz     = vu >> 2;        // key pair (2vz, 2vz+1)
  const int vh     = (vu >> 1) & 1;
  const int vjh    = vu & 1;
  const int vs2    = vz >> 4;
  const int vrow0  = vh * 8 + vjh * 4;
  const int vc     = ((vz >> 1) & 3) * 8 + ((vz >> 3) & 1) * 4 + (vz & 1) * 2;

  const bf16u* kbase = qkv + (((size_t)b * 16 + hg * 2 + s_hp) * 3 + 1) * E_ * 16 + s_half * 8;
  const bf16u* vbase = qkv + (((size_t)b * 16 + hg * 2 + s_hp) * 3 + 2) * E_ * 16 + vrow0;
  const int* sbp = sb + ((size_t)(b * E_) + q0w + l15) * E_;

  f32x4 accO[2];
  const f32x4 z4 = {0.f, 0.f, 0.f, 0.f};
  accO[0] = z4; accO[1] = z4;
  float lsum[2] = {0.f, 0.f};

  // ---- prologue: issue chunk-0 loads (latency overlaps zero-fill+barrier)
  uint4 kA;
  uint2 va, vb;
  unsigned mA;
  int sraw[2][2][4];
  {
    kA = *(const uint4*)(kbase + (size_t)s_key * 16);
    const bf16u* p0 = vbase + (size_t)(2 * vz) * 16;
    va = *(const uint2*)p0;
    vb = *(const uint2*)(p0 + 16);
    mA = mask[b * E_ + s_key];
#pragma unroll
    for (int s2 = 0; s2 < 2; ++s2)
#pragma unroll
      for (int kb2 = 0; kb2 < 2; ++kb2)
        *(int4*)&sraw[s2][kb2][0] =
            *(const int4*)(sbp + s2 * 32 + kb2 * 16 + quad * 4);
  }
  __syncthreads();   // zero-fill + emb2 visible before first staging write

#pragma unroll 2
  for (int i = 0; i < 16; ++i) {
    const int cur = i & 1;

    // ---- stage chunk i from regs -> LDS[cur]
    *(uint4*)&Kl[cur][s_hp][s_key][s_half * 8] = kA;
    {
      union { uint2 u; bf16u e[4]; } a, c; a.u = va; c.u = vb;
#pragma unroll
      for (int j = 0; j < 4; ++j)
        *(unsigned*)&Vt[cur][s_hp][vs2][vrow0 + j][vc] =
            (unsigned)a.e[j] | ((unsigned)c.e[j] << 16);
    }
    if (s_half == 0)
      Kl[cur][s_hp][s_key][16] = mA ? (bf16u)0xCF6E : (bf16u)0;

    __syncthreads();   // chunk i visible; buf^1 free (all waves past compute i-1)

    // ---- issue chunk i+1 loads: land during compute i (hidden latency)
    int srn[2][2][4];
    if (i < 15) {
      const int kn = (i + 1) * 64;
      kA = *(const uint4*)(kbase + (size_t)(kn + s_key) * 16);
      const bf16u* p0 = vbase + (size_t)(kn + 2 * vz) * 16;
      va = *(const uint2*)p0;
      vb = *(const uint2*)(p0 + 16);
      mA = mask[b * E_ + kn + s_key];
#pragma unroll
      for (int s2 = 0; s2 < 2; ++s2)
#pragma unroll
        for (int kb2 = 0; kb2 < 2; ++kb2)
          *(int4*)&srn[s2][kb2][0] =
              *(const int4*)(sbp + kn + s2 * 32 + kb2 * 16 + quad * 4);
    }

    // ---- compute chunk i (verbatim R3/R4 math, reading buf[cur])
    __builtin_amdgcn_s_setprio(1);
#pragma unroll
    for (int s2 = 0; s2 < 2; ++s2) {
      short8 k00 = *(const short8*)&Kl[cur][0][s2 * 32 + l15][quad * 8];
      short8 k01 = *(const short8*)&Kl[cur][0][s2 * 32 + 16 + l15][quad * 8];
      short8 k10 = *(const short8*)&Kl[cur][1][s2 * 32 + l15][quad * 8];
      short8 k11 = *(const short8*)&Kl[cur][1][s2 * 32 + 16 + l15][quad * 8];
      // swapped: C[key (quad*4+r)][q (l15)]
      f32x4 sc00 = __builtin_amdgcn_mfma_f32_16x16x32_bf16(k00, qf[0], z4, 0, 0, 0);
      f32x4 sc01 = __builtin_amdgcn_mfma_f32_16x16x32_bf16(k01, qf[0], z4, 0, 0, 0);
      f32x4 sc10 = __builtin_amdgcn_mfma_f32_16x16x32_bf16(k10, qf[1], z4, 0, 0, 0);
      f32x4 sc11 = __builtin_amdgcn_mfma_f32_16x16x32_bf16(k11, qf[1], z4, 0, 0, 0);

      unsigned pk0[4], pk1[4];
#pragma unroll
      for (int r = 0; r < 4; ++r) {
        float2 w0 = *(const float2*)&emb2[sraw[s2][0][r]][0];
        float2 w1 = *(const float2*)&emb2[sraw[s2][1][r]][0];
        float p00 = __builtin_amdgcn_exp2f(fmaf(sc00[r], C2, w0.x));  // hp0 kb0
        float p01 = __builtin_amdgcn_exp2f(fmaf(sc01[r], C2, w1.x));  // hp0 kb1
        float p10 = __builtin_amdgcn_exp2f(fmaf(sc10[r], C2, w0.y));  // hp1 kb0
        float p11 = __builtin_amdgcn_exp2f(fmaf(sc11[r], C2, w1.y));  // hp1 kb1
        unsigned u00 = __float_as_uint(p00), u01 = __float_as_uint(p01);
        unsigned u10 = __float_as_uint(p10), u11 = __float_as_uint(p11);
        lsum[0] += __uint_as_float(u00 & 0xffff0000u) + __uint_as_float(u01 & 0xffff0000u);
        lsum[1] += __uint_as_float(u10 & 0xffff0000u) + __uint_as_float(u11 & 0xffff0000u);
        if ((r & 1) == 0) {
          pk0[r >> 1]       = u00 >> 16;
          pk0[2 + (r >> 1)] = u01 >> 16;
          pk1[r >> 1]       = u10 >> 16;
          pk1[2 + (r >> 1)] = u11 >> 16;
        } else {
          pk0[r >> 1]       |= u00 & 0xffff0000u;
          pk0[2 + (r >> 1)] |= u01 & 0xffff0000u;
          pk1[r >> 1]       |= u10 & 0xffff0000u;
          pk1[2 + (r >> 1)] |= u11 & 0xffff0000u;
        }
      }
      union { unsigned u[4]; short8 s; } a0, a1;
      a0.u[0] = pk0[0]; a0.u[1] = pk0[1]; a0.u[2] = pk0[2]; a0.u[3] = pk0[3];
      a1.u[0] = pk1[0]; a1.u[1] = pk1[1]; a1.u[2] = pk1[2]; a1.u[3] = pk1[3];

      short8 vf0 = *(const short8*)&Vt[cur][0][s2][l15][quad * 8];
      short8 vf1 = *(const short8*)&Vt[cur][1][s2][l15][quad * 8];
      accO[0] = __builtin_amdgcn_mfma_f32_16x16x32_bf16(a0.s, vf0, accO[0], 0, 0, 0);
      accO[1] = __builtin_amdgcn_mfma_f32_16x16x32_bf16(a1.s, vf1, accO[1], 0, 0, 0);
    }
    __builtin_amdgcn_s_setprio(0);

    // ---- rotate sb regs
    if (i < 15) {
#pragma unroll
      for (int s2 = 0; s2 < 2; ++s2)
#pragma unroll
        for (int kb2 = 0; kb2 < 2; ++kb2)
#pragma unroll
          for (int r = 0; r < 4; ++r)
            sraw[s2][kb2][r] = srn[s2][kb2][r];
    }
  }

  // lsum per-q on l15 (quads hold disjoint key subsets): reduce, then
  // redistribute to C-layout rows (q = quad*4 + r).
#pragma unroll
  for (int hp = 0; hp < 2; ++hp) {
    lsum[hp] += __shfl_xor(lsum[hp], 16, 64);
    lsum[hp] += __shfl_xor(lsum[hp], 32, 64);
  }
#pragma unroll
  for (int hp = 0; hp < 2; ++hp) {
#pragma unroll
    for (int r = 0; r < 4; ++r) {
      float lq = __shfl(lsum[hp], quad * 4 + r, 64);
      float o = accO[hp][r] / lq;
      O[((size_t)(b * E_) + q0w + quad * 4 + r) * 256 + (hg * 2 + hp) * 16 + l15] = f2bf(o);
    }
  }
}

// ---------------------------------------------------------------------------
// LayerNorm, one wave per row of 256. DUAL: also write bf16 copy.
// ---------------------------------------------------------------------------
template<int DUAL>
__global__ __launch_bounds__(256) void ln_k(
    const float* __restrict__ X, const float* __restrict__ g,
    const float* __restrict__ bta, float* __restrict__ Y, bf16u* __restrict__ Yb)
{
  const int row  = blockIdx.x * 4 + (threadIdx.x >> 6);
  const int lane = threadIdx.x & 63;
  float4 v = *(const float4*)(X + (size_t)row * D_ + lane * 4);
  float s  = v.x + v.y + v.z + v.w;
  float ss = v.x * v.x + v.y * v.y + v.z * v.z + v.w * v.w;
#pragma unroll
  for (int off = 32; off; off >>= 1) {
    s  += __shfl_xor(s, off, 64);
    ss += __shfl_xor(ss, off, 64);
  }
  float mu  = s * (1.f / 256.f);
  float var = ss * (1.f / 256.f) - mu * mu;
  float rs  = 1.f / sqrtf(var + 1e-5f);
  float4 gv = *(const float4*)(g + lane * 4);
  float4 bv = *(const float4*)(bta + lane * 4);
  float4 o;
  o.x = (v.x - mu) * rs * gv.x + bv.x;
  o.y = (v.y - mu) * rs * gv.y + bv.y;
  o.z = (v.z - mu) * rs * gv.z + bv.z;
  o.w = (v.w - mu) * rs * gv.w + bv.w;
  *(float4*)(Y + (size_t)row * D_ + lane * 4) = o;
  if (DUAL) {
    uint2 p;
    p.x = f2bf(o.x) | ((unsigned)f2bf(o.y) << 16);
    p.y = f2bf(o.z) | ((unsigned)f2bf(o.w) << 16);
    *(uint2*)(Yb + (size_t)row * D_ + lane * 4) = p;
  }
}

// ---------------------------------------------------------------------------
extern "C" void kernel_launch(void* const* d_in, const int* in_sizes, int n_in,
                              void* d_out, int out_size, void* d_ws, size_t ws_size,
                              hipStream_t stream) {
  const float* x   = (const float*)d_in[0];
  const int*   sb  = (const int*)d_in[1];
  const unsigned char* mask = (const unsigned char*)d_in[2];
  const float* Wq  = (const float*)d_in[3];
  const float* bq  = (const float*)d_in[4];
  const float* Wk  = (const float*)d_in[5];
  const float* bk  = (const float*)d_in[6];
  const float* Wv  = (const float*)d_in[7];
  const float* bv  = (const float*)d_in[8];
  const float* Wo  = (const float*)d_in[9];
  const float* bo  = (const float*)d_in[10];
  const float* be  = (const float*)d_in[11];
  const float* g1  = (const float*)d_in[12];
  const float* b1  = (const float*)d_in[13];
  const float* Wf1 = (const float*)d_in[14];
  const float* bf1 = (const float*)d_in[15];
  const float* Wf2 = (const float*)d_in[16];
  const float* bf2 = (const float*)d_in[17];
  const float* g2  = (const float*)d_in[18];
  const float* b2  = (const float*)d_in[19];
  float* out = (float*)d_out;

  char* ws = (char*)d_ws;
  bf16u* Wqkvt = (bf16u*)(ws + 0);          // 768*256*2
  bf16u* Wot   = (bf16u*)(ws + 393216);     // 256*256*2
  bf16u* Wf1t  = (bf16u*)(ws + 524288);     // 1024*256*2
  bf16u* Wf2t  = (bf16u*)(ws + 1048576);    // 256*1024*2
  float* bqkv  = (float*)(ws + 1572864);    // 768*4
  bf16u* xb    = (bf16u*)(ws + 2097152);    // 4 MB   [dead after qkv gemm]
  bf16u* qkv   = (bf16u*)(ws + 6291456);    // 12.6 MB [dead after attn]
  bf16u* att   = (bf16u*)(ws + 18874368);   // 4 MB
  float* t1    = (float*)(ws + 23068672);   // 8 MB   [dead after ln1]
  float* x1    = (float*)(ws + 31457280);   // 8 MB
  bf16u* x1b   = (bf16u*)(ws + 39845888);   // 4 MB
  bf16u* ffh   = (bf16u*)(ws + 2097152);    // 16 MB, reuses xb+qkv
  float* t2    = (float*)(ws + 18874368);   // 8 MB, reuses att+t1

  dim3 blk(256);

  prep_k<<<1795, blk, 0, stream>>>(Wq, Wk, Wv, Wo, Wf1, Wf2,
                                   Wqkvt, Wot, Wf1t, Wf2t,
                                   bq, bk, bv, bqkv, x, xb);

  // QKV projection -> qkv bf16 in permuted [b][head][type][e][16] layout
  // (pipelined 64x64 tiles; grid 1536 blocks, 2/CU)
  mm_k<64, 64, 3><<<dim3(128, 12), blk, 0, stream>>>(xb, Wqkvt, bqkv, nullptr,
                                                     qkv, M_, 768, 256);
  // MFMA flash attention -> att bf16 (R12 pipeline + setprio, unchanged)
  attn_k<<<dim3(16, 8, 8), blk, 0, stream>>>(qkv, sb, mask, be, att);

  // out-proj + residual -> t1 fp32; ln1 -> x1 fp32 + x1b bf16
  mm_k<64, 64, 1><<<dim3(128, 4), blk, 0, stream>>>(att, Wot, bo, x,
                                                    t1, M_, 256, 256);
  ln_k<1><<<M_ / 4, blk, 0, stream>>>(t1, g1, b1, x1, x1b);

  // FFN
  mm_k<64, 64, 2><<<dim3(128, 16), blk, 0, stream>>>(x1b, Wf1t, bf1, nullptr,
                                                     ffh, M_, 1024, 256);
  mm_k<64, 64, 1><<<dim3(128, 4), blk, 0, stream>>>(ffh, Wf2t, bf2, x1,
                                                    t2, M_, 256, 1024);
  ln_k<0><<<M_ / 4, blk, 0, stream>>>(t2, g2, b2, out, nullptr);
}

// Round 14
// 225.166 us; speedup vs baseline: 1.0268x; 1.0268x over previous
//
#include <hip/hip_runtime.h>
#include <math.h>

#define B_  8
#define E_  1024
#define D_  256
#define H_  16
#define FF_ 1024
#define M_  (B_ * E_)   // 8192 rows

typedef __attribute__((ext_vector_type(8))) short short8;
typedef __attribute__((ext_vector_type(4))) float f32x4;
typedef unsigned short bf16u;

#define GLOAD_LDS16(g, l) __builtin_amdgcn_global_load_lds( \
    (const __attribute__((address_space(1))) void*)(g), \
    (__attribute__((address_space(3))) void*)(l), 16, 0, 0)

__device__ __forceinline__ unsigned short f2bf(float f) {
  union { float f; unsigned u; } c; c.f = f;
  unsigned r = c.u + 0x7fffu + ((c.u >> 16) & 1u);   // RNE
  return (unsigned short)(r >> 16);
}
__device__ __forceinline__ float gelu_exact(float x) {
  return 0.5f * x * (1.0f + erff(x * 0.70710678118654752f));
}

// ---------------------------------------------------------------------------
// bf16 MFMA GEMM.
// PIPE=0: R12-proven 2-barrier loop (single LDS buffer) — best measured for
//         the big-tile QKV/FF1 shapes.
// PIPE=1: single-barrier double-buffered pipeline (attn-style) — A/B'd on
//         the small 64x64 Wo/FF2 shapes at fixed tile size.
// EPI: 0 = bf16 out (+bias); 1 = f32 out (+bias+R residual); 2 = bf16 gelu;
//      3 = bf16 out (+bias), permuted store qkv[b][head][type][e][16].
// ---------------------------------------------------------------------------
template<int BM, int BN, int EPI, int PIPE>
__global__ __launch_bounds__(256) void mm_k(
    const bf16u* __restrict__ A, const bf16u* __restrict__ Wt,
    const float* __restrict__ bias, const float* __restrict__ R,
    void* __restrict__ Cout, int M, int N, int K)
{
  constexpr int WM = BM / 2, WN = BN / 2;
  constexpr int MT = WM / 16, NT = WN / 16;
  constexpr int PA = BM * 8 / 256, PB = BN * 8 / 256;
  constexpr int LBM = (BM == 128 ? 7 : 6), LBN = (BN == 128 ? 7 : 6);
  constexpr int NBUF = PIPE ? 2 : 1;
  __shared__ bf16u As[NBUF][BM * 64];
  __shared__ bf16u Bs[NBUF][BN * 64];

  const int t = threadIdx.x;
  const int l15 = t & 15, quad = (t >> 4) & 3;
  const int w = t >> 6, wm = w >> 1, wn = w & 1;
  const int m0 = blockIdx.x * BM, n0 = blockIdx.y * BN;

  f32x4 acc[MT][NT];
  const f32x4 z4 = {0.f, 0.f, 0.f, 0.f};
#pragma unroll
  for (int i = 0; i < MT; ++i)
#pragma unroll
    for (int j = 0; j < NT; ++j) acc[i][j] = z4;

  if (PIPE) {
    const int NK = K >> 6;
    // prologue: stage k-step 0 into buffer 0
#pragma unroll
    for (int p = 0; p < PA; ++p) {
      int g = p * 256 + t;
      int m = g & (BM - 1), c = g >> LBM;
      GLOAD_LDS16(A + (size_t)(m0 + m) * K + c * 8, &As[0][g * 8]);
    }
#pragma unroll
    for (int p = 0; p < PB; ++p) {
      int g = p * 256 + t;
      int n = g & (BN - 1), c = g >> LBN;
      GLOAD_LDS16(Wt + (size_t)(n0 + n) * K + c * 8, &Bs[0][g * 8]);
    }
    __syncthreads();

    for (int ki = 0; ki < NK; ++ki) {
      const int cur = ki & 1;
      if (ki + 1 < NK) {
        const int k0 = (ki + 1) << 6;
#pragma unroll
        for (int p = 0; p < PA; ++p) {
          int g = p * 256 + t;
          int m = g & (BM - 1), c = g >> LBM;
          GLOAD_LDS16(A + (size_t)(m0 + m) * K + k0 + c * 8, &As[(cur ^ 1) & (NBUF - 1)][g * 8]);
        }
#pragma unroll
        for (int p = 0; p < PB; ++p) {
          int g = p * 256 + t;
          int n = g & (BN - 1), c = g >> LBN;
          GLOAD_LDS16(Wt + (size_t)(n0 + n) * K + k0 + c * 8, &Bs[(cur ^ 1) & (NBUF - 1)][g * 8]);
        }
      }
#pragma unroll
      for (int s = 0; s < 2; ++s) {
        short8 af[MT], bfr[NT];
#pragma unroll
        for (int mt = 0; mt < MT; ++mt)
          af[mt] = *(const short8*)(&As[cur & (NBUF - 1)][((s * 4 + quad) * BM + wm * WM + mt * 16 + l15) * 8]);
#pragma unroll
        for (int nt = 0; nt < NT; ++nt)
          bfr[nt] = *(const short8*)(&Bs[cur & (NBUF - 1)][((s * 4 + quad) * BN + wn * WN + nt * 16 + l15) * 8]);
#pragma unroll
        for (int mt = 0; mt < MT; ++mt)
#pragma unroll
          for (int nt = 0; nt < NT; ++nt)
            acc[mt][nt] = __builtin_amdgcn_mfma_f32_16x16x32_bf16(
                af[mt], bfr[nt], acc[mt][nt], 0, 0, 0);
      }
      __syncthreads();
    }
  } else {
    for (int k0 = 0; k0 < K; k0 += 64) {
      __syncthreads();
#pragma unroll
      for (int p = 0; p < PA; ++p) {
        int g = p * 256 + t;
        int m = g & (BM - 1), c = g >> LBM;
        GLOAD_LDS16(A + (size_t)(m0 + m) * K + k0 + c * 8, &As[0][g * 8]);
      }
#pragma unroll
      for (int p = 0; p < PB; ++p) {
        int g = p * 256 + t;
        int n = g & (BN - 1), c = g >> LBN;
        GLOAD_LDS16(Wt + (size_t)(n0 + n) * K + k0 + c * 8, &Bs[0][g * 8]);
      }
      __syncthreads();
#pragma unroll
      for (int s = 0; s < 2; ++s) {
        short8 af[MT], bfr[NT];
#pragma unroll
        for (int mt = 0; mt < MT; ++mt)
          af[mt] = *(const short8*)(&As[0][((s * 4 + quad) * BM + wm * WM + mt * 16 + l15) * 8]);
#pragma unroll
        for (int nt = 0; nt < NT; ++nt)
          bfr[nt] = *(const short8*)(&Bs[0][((s * 4 + quad) * BN + wn * WN + nt * 16 + l15) * 8]);
#pragma unroll
        for (int mt = 0; mt < MT; ++mt)
#pragma unroll
          for (int nt = 0; nt < NT; ++nt)
            acc[mt][nt] = __builtin_amdgcn_mfma_f32_16x16x32_bf16(
                af[mt], bfr[nt], acc[mt][nt], 0, 0, 0);
      }
    }
  }

#pragma unroll
  for (int mt = 0; mt < MT; ++mt) {
#pragma unroll
    for (int nt = 0; nt < NT; ++nt) {
      int col = n0 + wn * WN + nt * 16 + l15;
      float bia = bias[col];
#pragma unroll
      for (int r = 0; r < 4; ++r) {
        int row = m0 + wm * WM + mt * 16 + quad * 4 + r;
        float v = acc[mt][nt][r] + bia;
        if (EPI == 3) {
          size_t pidx = ((((size_t)(row >> 10) * 16 + ((col >> 4) & 15)) * 3 +
                          (col >> 8)) * E_ + (row & 1023)) * 16 + (col & 15);
          ((bf16u*)Cout)[pidx] = f2bf(v);
        } else {
          size_t idx = (size_t)row * N + col;
          if (EPI == 1)      { ((float*)Cout)[idx] = v + R[idx]; }
          else if (EPI == 2) { ((bf16u*)Cout)[idx] = f2bf(gelu_exact(v)); }
          else               { ((bf16u*)Cout)[idx] = f2bf(v); }
        }
      }
    }
  }
}

// ---------------------------------------------------------------------------
// Fused prep: weight transposes + bias concat + x conversion, 1 launch.
// ---------------------------------------------------------------------------
__global__ __launch_bounds__(256) void prep_k(
    const float* __restrict__ Wq, const float* __restrict__ Wk,
    const float* __restrict__ Wv, const float* __restrict__ Wo,
    const float* __restrict__ Wf1, const float* __restrict__ Wf2,
    bf16u* __restrict__ Wqkvt, bf16u* __restrict__ Wot,
    bf16u* __restrict__ Wf1t, bf16u* __restrict__ Wf2t,
    const float* __restrict__ bq, const float* __restrict__ bk,
    const float* __restrict__ bv, float* __restrict__ bqkv,
    const float* __restrict__ X, bf16u* __restrict__ Xb)
{
  __shared__ float tile[32][33];
  const int gid = blockIdx.x;
  const int t = threadIdx.x;

  if (gid < 768) {
    const float* src; bf16u* dst; int K, N, bx, by;
    if (gid < 256) {
      const int z = gid >> 6, r = gid & 63;
      src = (z == 0) ? Wq : (z == 1) ? Wk : (z == 2) ? Wv : Wo;
      dst = (z == 0) ? Wqkvt : (z == 1) ? Wqkvt + 65536
          : (z == 2) ? Wqkvt + 131072 : Wot;
      K = 256; N = 256; bx = r & 7; by = r >> 3;
    } else if (gid < 512) {
      const int r = gid - 256;
      src = Wf1; dst = Wf1t; K = 256; N = 1024; bx = r & 7; by = r >> 3;
    } else {
      const int r = gid - 512;
      src = Wf2; dst = Wf2t; K = 1024; N = 256; bx = r & 31; by = r >> 5;
    }
    const int tx = t & 31, ty = t >> 5;
    const int kb = bx * 32, nb = by * 32;
#pragma unroll
    for (int r = 0; r < 4; ++r)
      tile[ty + 8 * r][tx] = src[(size_t)(kb + ty + 8 * r) * N + nb + tx];
    __syncthreads();
#pragma unroll
    for (int r = 0; r < 4; ++r)
      dst[(size_t)(nb + ty + 8 * r) * K + kb + tx] = f2bf(tile[tx][ty + 8 * r]);
  } else if (gid < 771) {
    int i = (gid - 768) * 256 + t;
    bqkv[i] = (i < 256) ? bq[i] : (i < 512) ? bk[i - 256] : bv[i - 512];
  } else {
    int i = (gid - 771) * 256 + t;
    float4 a = ((const float4*)X)[i * 2];
    float4 b = ((const float4*)X)[i * 2 + 1];
    uint4 o;
    o.x = f2bf(a.x) | ((unsigned)f2bf(a.y) << 16);
    o.y = f2bf(a.z) | ((unsigned)f2bf(a.w) << 16);
    o.z = f2bf(b.x) | ((unsigned)f2bf(b.y) << 16);
    o.w = f2bf(b.z) | ((unsigned)f2bf(b.w) << 16);
    ((uint4*)Xb)[i] = o;
  }
}

// ---------------------------------------------------------------------------
// MFMA flash attention — R12 best-measured version, byte-identical
// (54.2-56 us: R9 coalesced-qkv pipeline + setprio T5).
// ---------------------------------------------------------------------------
__global__ __launch_bounds__(256) void attn_k(
    const bf16u* __restrict__ qkv, const int* __restrict__ sb,
    const unsigned char* __restrict__ mask, const float* __restrict__ be,
    bf16u* __restrict__ O)
{
  __shared__ bf16u Kl[2][2][64][40];     // [buf][hp][key][d0-15,mask@16,0@17-31,pad]
  __shared__ bf16u Vt[2][2][2][16][40];  // [buf][hp][s2][d][32 permuted slots+pad]
  __shared__ float emb2[6][2];           // [s][hp] pre-scaled by log2e

  const int t    = threadIdx.x;
  const int b    = blockIdx.z;
  const int hg   = blockIdx.y;          // head pair 0..7
  const int w    = t >> 6;
  const int lane = t & 63;
  const int l15  = lane & 15;
  const int quad = lane >> 4;
  const int q0w  = blockIdx.x * 64 + w * 16;
  const float C2 = 0.36067376022224085f;   // 0.25 * log2(e)

  if (t < 12) emb2[t >> 1][t & 1] = be[(t >> 1) * 16 + hg * 2 + (t & 1)] * 1.44269504088896f;

  {  // zero both Kl buffers: cols 17..31 must stay 0 for the padded MFMA
    float4 z = {0.f, 0.f, 0.f, 0.f};
    float4* kp = (float4*)&Kl[0][0][0][0];
    for (int i = t; i < 1280; i += 256) kp[i] = z;
  }

  // Q B-frag: lane l15 = q, elems = d (quad*8+j); quads 2,3 zero-pad except
  // d=16 (quad2,j0) = 1.0 for the mask-inject trick.
  short8 qf[2];
#pragma unroll
  for (int hp = 0; hp < 2; ++hp) {
    uint4 v = {0u, 0u, 0u, 0u};
    if (quad < 2)
      v = *(const uint4*)(qkv +
          ((((size_t)b * 16 + hg * 2 + hp) * 3 + 0) * E_ + q0w + l15) * 16 + quad * 8);
    else if (quad == 2)
      v.x = 0x3F80u;  // bf16 1.0 (mask-inject slot d=16)
    union { uint4 u; short8 s; } c; c.u = v;
    qf[hp] = c.s;
  }

  // staging roles
  const int s_hp   = t >> 7;         // K/V: which head
  const int s_key  = (t >> 1) & 63;  // K: key
  const int s_half = t & 1;          // K: d-half
  const int vu     = t & 127;
  const int vz     = vu >> 2;        // key pair (2vz, 2vz+1)
  const int vh     = (vu >> 1) & 1;
  const int vjh    = vu & 1;
  const int vs2    = vz >> 4;
  const int vrow0  = vh * 8 + vjh * 4;
  const int vc     = ((vz >> 1) & 3) * 8 + ((vz >> 3) & 1) * 4 + (vz & 1) * 2;

  const bf16u* kbase = qkv + (((size_t)b * 16 + hg * 2 + s_hp) * 3 + 1) * E_ * 16 + s_half * 8;
  const bf16u* vbase = qkv + (((size_t)b * 16 + hg * 2 + s_hp) * 3 + 2) * E_ * 16 + vrow0;
  const int* sbp = sb + ((size_t)(b * E_) + q0w + l15) * E_;

  f32x4 accO[2];
  const f32x4 z4 = {0.f, 0.f, 0.f, 0.f};
  accO[0] = z4; accO[1] = z4;
  float lsum[2] = {0.f, 0.f};

  // ---- prologue: issue chunk-0 loads (latency overlaps zero-fill+barrier)
  uint4 kA;
  uint2 va, vb;
  unsigned mA;
  int sraw[2][2][4];
  {
    kA = *(const uint4*)(kbase + (size_t)s_key * 16);
    const bf16u* p0 = vbase + (size_t)(2 * vz) * 16;
    va = *(const uint2*)p0;
    vb = *(const uint2*)(p0 + 16);
    mA = mask[b * E_ + s_key];
#pragma unroll
    for (int s2 = 0; s2 < 2; ++s2)
#pragma unroll
      for (int kb2 = 0; kb2 < 2; ++kb2)
        *(int4*)&sraw[s2][kb2][0] =
            *(const int4*)(sbp + s2 * 32 + kb2 * 16 + quad * 4);
  }
  __syncthreads();   // zero-fill + emb2 visible before first staging write

#pragma unroll 2
  for (int i = 0; i < 16; ++i) {
    const int cur = i & 1;

    // ---- stage chunk i from regs -> LDS[cur]
    *(uint4*)&Kl[cur][s_hp][s_key][s_half * 8] = kA;
    {
      union { uint2 u; bf16u e[4]; } a, c; a.u = va; c.u = vb;
#pragma unroll
      for (int j = 0; j < 4; ++j)
        *(unsigned*)&Vt[cur][s_hp][vs2][vrow0 + j][vc] =
            (unsigned)a.e[j] | ((unsigned)c.e[j] << 16);
    }
    if (s_half == 0)
      Kl[cur][s_hp][s_key][16] = mA ? (bf16u)0xCF6E : (bf16u)0;

    __syncthreads();   // chunk i visible; buf^1 free (all waves past compute i-1)

    // ---- issue chunk i+1 loads: land during compute i (hidden latency)
    int srn[2][2][4];
    if (i < 15) {
      const int kn = (i + 1) * 64;
      kA = *(const uint4*)(kbase + (size_t)(kn + s_key) * 16);
      const bf16u* p0 = vbase + (size_t)(kn + 2 * vz) * 16;
      va = *(const uint2*)p0;
      vb = *(const uint2*)(p0 + 16);
      mA = mask[b * E_ + kn + s_key];
#pragma unroll
      for (int s2 = 0; s2 < 2; ++s2)
#pragma unroll
        for (int kb2 = 0; kb2 < 2; ++kb2)
          *(int4*)&srn[s2][kb2][0] =
              *(const int4*)(sbp + kn + s2 * 32 + kb2 * 16 + quad * 4);
    }

    // ---- compute chunk i (verbatim R3/R4 math, reading buf[cur])
    __builtin_amdgcn_s_setprio(1);
#pragma unroll
    for (int s2 = 0; s2 < 2; ++s2) {
      short8 k00 = *(const short8*)&Kl[cur][0][s2 * 32 + l15][quad * 8];
      short8 k01 = *(const short8*)&Kl[cur][0][s2 * 32 + 16 + l15][quad * 8];
      short8 k10 = *(const short8*)&Kl[cur][1][s2 * 32 + l15][quad * 8];
      short8 k11 = *(const short8*)&Kl[cur][1][s2 * 32 + 16 + l15][quad * 8];
      // swapped: C[key (quad*4+r)][q (l15)]
      f32x4 sc00 = __builtin_amdgcn_mfma_f32_16x16x32_bf16(k00, qf[0], z4, 0, 0, 0);
      f32x4 sc01 = __builtin_amdgcn_mfma_f32_16x16x32_bf16(k01, qf[0], z4, 0, 0, 0);
      f32x4 sc10 = __builtin_amdgcn_mfma_f32_16x16x32_bf16(k10, qf[1], z4, 0, 0, 0);
      f32x4 sc11 = __builtin_amdgcn_mfma_f32_16x16x32_bf16(k11, qf[1], z4, 0, 0, 0);

      unsigned pk0[4], pk1[4];
#pragma unroll
      for (int r = 0; r < 4; ++r) {
        float2 w0 = *(const float2*)&emb2[sraw[s2][0][r]][0];
        float2 w1 = *(const float2*)&emb2[sraw[s2][1][r]][0];
        float p00 = __builtin_amdgcn_exp2f(fmaf(sc00[r], C2, w0.x));  // hp0 kb0
        float p01 = __builtin_amdgcn_exp2f(fmaf(sc01[r], C2, w1.x));  // hp0 kb1
        float p10 = __builtin_amdgcn_exp2f(fmaf(sc10[r], C2, w0.y));  // hp1 kb0
        float p11 = __builtin_amdgcn_exp2f(fmaf(sc11[r], C2, w1.y));  // hp1 kb1
        unsigned u00 = __float_as_uint(p00), u01 = __float_as_uint(p01);
        unsigned u10 = __float_as_uint(p10), u11 = __float_as_uint(p11);
        lsum[0] += __uint_as_float(u00 & 0xffff0000u) + __uint_as_float(u01 & 0xffff0000u);
        lsum[1] += __uint_as_float(u10 & 0xffff0000u) + __uint_as_float(u11 & 0xffff0000u);
        if ((r & 1) == 0) {
          pk0[r >> 1]       = u00 >> 16;
          pk0[2 + (r >> 1)] = u01 >> 16;
          pk1[r >> 1]       = u10 >> 16;
          pk1[2 + (r >> 1)] = u11 >> 16;
        } else {
          pk0[r >> 1]       |= u00 & 0xffff0000u;
          pk0[2 + (r >> 1)] |= u01 & 0xffff0000u;
          pk1[r >> 1]       |= u10 & 0xffff0000u;
          pk1[2 + (r >> 1)] |= u11 & 0xffff0000u;
        }
      }
      union { unsigned u[4]; short8 s; } a0, a1;
      a0.u[0] = pk0[0]; a0.u[1] = pk0[1]; a0.u[2] = pk0[2]; a0.u[3] = pk0[3];
      a1.u[0] = pk1[0]; a1.u[1] = pk1[1]; a1.u[2] = pk1[2]; a1.u[3] = pk1[3];

      short8 vf0 = *(const short8*)&Vt[cur][0][s2][l15][quad * 8];
      short8 vf1 = *(const short8*)&Vt[cur][1][s2][l15][quad * 8];
      accO[0] = __builtin_amdgcn_mfma_f32_16x16x32_bf16(a0.s, vf0, accO[0], 0, 0, 0);
      accO[1] = __builtin_amdgcn_mfma_f32_16x16x32_bf16(a1.s, vf1, accO[1], 0, 0, 0);
    }
    __builtin_amdgcn_s_setprio(0);

    // ---- rotate sb regs
    if (i < 15) {
#pragma unroll
      for (int s2 = 0; s2 < 2; ++s2)
#pragma unroll
        for (int kb2 = 0; kb2 < 2; ++kb2)
#pragma unroll
          for (int r = 0; r < 4; ++r)
            sraw[s2][kb2][r] = srn[s2][kb2][r];
    }
  }

  // lsum per-q on l15 (quads hold disjoint key subsets): reduce, then
  // redistribute to C-layout rows (q = quad*4 + r).
#pragma unroll
  for (int hp = 0; hp < 2; ++hp) {
    lsum[hp] += __shfl_xor(lsum[hp], 16, 64);
    lsum[hp] += __shfl_xor(lsum[hp], 32, 64);
  }
#pragma unroll
  for (int hp = 0; hp < 2; ++hp) {
#pragma unroll
    for (int r = 0; r < 4; ++r) {
      float lq = __shfl(lsum[hp], quad * 4 + r, 64);
      float o = accO[hp][r] / lq;
      O[((size_t)(b * E_) + q0w + quad * 4 + r) * 256 + (hg * 2 + hp) * 16 + l15] = f2bf(o);
    }
  }
}

// ---------------------------------------------------------------------------
// LayerNorm, one wave per row of 256. DUAL: also write bf16 copy.
// ---------------------------------------------------------------------------
template<int DUAL>
__global__ __launch_bounds__(256) void ln_k(
    const float* __restrict__ X, const float* __restrict__ g,
    const float* __restrict__ bta, float* __restrict__ Y, bf16u* __restrict__ Yb)
{
  const int row  = blockIdx.x * 4 + (threadIdx.x >> 6);
  const int lane = threadIdx.x & 63;
  float4 v = *(const float4*)(X + (size_t)row * D_ + lane * 4);
  float s  = v.x + v.y + v.z + v.w;
  float ss = v.x * v.x + v.y * v.y + v.z * v.z + v.w * v.w;
#pragma unroll
  for (int off = 32; off; off >>= 1) {
    s  += __shfl_xor(s, off, 64);
    ss += __shfl_xor(ss, off, 64);
  }
  float mu  = s * (1.f / 256.f);
  float var = ss * (1.f / 256.f) - mu * mu;
  float rs  = 1.f / sqrtf(var + 1e-5f);
  float4 gv = *(const float4*)(g + lane * 4);
  float4 bv = *(const float4*)(bta + lane * 4);
  float4 o;
  o.x = (v.x - mu) * rs * gv.x + bv.x;
  o.y = (v.y - mu) * rs * gv.y + bv.y;
  o.z = (v.z - mu) * rs * gv.z + bv.z;
  o.w = (v.w - mu) * rs * gv.w + bv.w;
  *(float4*)(Y + (size_t)row * D_ + lane * 4) = o;
  if (DUAL) {
    uint2 p;
    p.x = f2bf(o.x) | ((unsigned)f2bf(o.y) << 16);
    p.y = f2bf(o.z) | ((unsigned)f2bf(o.w) << 16);
    *(uint2*)(Yb + (size_t)row * D_ + lane * 4) = p;
  }
}

// ---------------------------------------------------------------------------
extern "C" void kernel_launch(void* const* d_in, const int* in_sizes, int n_in,
                              void* d_out, int out_size, void* d_ws, size_t ws_size,
                              hipStream_t stream) {
  const float* x   = (const float*)d_in[0];
  const int*   sb  = (const int*)d_in[1];
  const unsigned char* mask = (const unsigned char*)d_in[2];
  const float* Wq  = (const float*)d_in[3];
  const float* bq  = (const float*)d_in[4];
  const float* Wk  = (const float*)d_in[5];
  const float* bk  = (const float*)d_in[6];
  const float* Wv  = (const float*)d_in[7];
  const float* bv  = (const float*)d_in[8];
  const float* Wo  = (const float*)d_in[9];
  const float* bo  = (const float*)d_in[10];
  const float* be  = (const float*)d_in[11];
  const float* g1  = (const float*)d_in[12];
  const float* b1  = (const float*)d_in[13];
  const float* Wf1 = (const float*)d_in[14];
  const float* bf1 = (const float*)d_in[15];
  const float* Wf2 = (const float*)d_in[16];
  const float* bf2 = (const float*)d_in[17];
  const float* g2  = (const float*)d_in[18];
  const float* b2  = (const float*)d_in[19];
  float* out = (float*)d_out;

  char* ws = (char*)d_ws;
  bf16u* Wqkvt = (bf16u*)(ws + 0);          // 768*256*2
  bf16u* Wot   = (bf16u*)(ws + 393216);     // 256*256*2
  bf16u* Wf1t  = (bf16u*)(ws + 524288);     // 1024*256*2
  bf16u* Wf2t  = (bf16u*)(ws + 1048576);    // 256*1024*2
  float* bqkv  = (float*)(ws + 1572864);    // 768*4
  bf16u* xb    = (bf16u*)(ws + 2097152);    // 4 MB   [dead after qkv gemm]
  bf16u* qkv   = (bf16u*)(ws + 6291456);    // 12.6 MB [dead after attn]
  bf16u* att   = (bf16u*)(ws + 18874368);   // 4 MB
  float* t1    = (float*)(ws + 23068672);   // 8 MB   [dead after ln1]
  float* x1    = (float*)(ws + 31457280);   // 8 MB
  bf16u* x1b   = (bf16u*)(ws + 39845888);   // 4 MB
  bf16u* ffh   = (bf16u*)(ws + 2097152);    // 16 MB, reuses xb+qkv
  float* t2    = (float*)(ws + 18874368);   // 8 MB, reuses att+t1

  dim3 blk(256);

  prep_k<<<1795, blk, 0, stream>>>(Wq, Wk, Wv, Wo, Wf1, Wf2,
                                   Wqkvt, Wot, Wf1t, Wf2t,
                                   bq, bk, bv, bqkv, x, xb);

  // QKV projection -> qkv bf16, permuted layout (R12-proven 2-barrier, 64x128)
  mm_k<64, 128, 3, 0><<<dim3(128, 6), blk, 0, stream>>>(xb, Wqkvt, bqkv, nullptr,
                                                        qkv, M_, 768, 256);
  // MFMA flash attention -> att bf16 (R12 pipeline + setprio, unchanged)
  attn_k<<<dim3(16, 8, 8), blk, 0, stream>>>(qkv, sb, mask, be, att);

  // out-proj + residual -> t1 fp32 (pipelined 64x64: pure pipeline A/B)
  mm_k<64, 64, 1, 1><<<dim3(128, 4), blk, 0, stream>>>(att, Wot, bo, x,
                                                       t1, M_, 256, 256);
  ln_k<1><<<M_ / 4, blk, 0, stream>>>(t1, g1, b1, x1, x1b);

  // FFN: FF1 R12-proven 2-barrier 128x128; FF2 pipelined 64x64
  mm_k<128, 128, 2, 0><<<dim3(64, 8), blk, 0, stream>>>(x1b, Wf1t, bf1, nullptr,
                                                        ffh, M_, 1024, 256);
  mm_k<64, 64, 1, 1><<<dim3(128, 4), blk, 0, stream>>>(ffh, Wf2t, bf2, x1,
                                                       t2, M_, 256, 1024);
  ln_k<0><<<M_ / 4, blk, 0, stream>>>(t2, g2, b2, out, nullptr);
}

// Round 15
// 224.763 us; speedup vs baseline: 1.0286x; 1.0018x over previous
//
#include <hip/hip_runtime.h>
#include <math.h>

#define B_  8
#define E_  1024
#define D_  256
#define H_  16
#define FF_ 1024
#define M_  (B_ * E_)   // 8192 rows

typedef __attribute__((ext_vector_type(8))) short short8;
typedef __attribute__((ext_vector_type(4))) float f32x4;
typedef unsigned short bf16u;

#define GLOAD_LDS16(g, l) __builtin_amdgcn_global_load_lds( \
    (const __attribute__((address_space(1))) void*)(g), \
    (__attribute__((address_space(3))) void*)(l), 16, 0, 0)

__device__ __forceinline__ unsigned short f2bf(float f) {
  union { float f; unsigned u; } c; c.f = f;
  unsigned r = c.u + 0x7fffu + ((c.u >> 16) & 1u);   // RNE
  return (unsigned short)(r >> 16);
}
__device__ __forceinline__ float gelu_exact(float x) {
  return 0.5f * x * (1.0f + erff(x * 0.70710678118654752f));
}

// ---------------------------------------------------------------------------
// bf16 MFMA GEMM, tiled BMxBN with K-step BK (32 or 64).
// PIPE=1: single-barrier double-buffered pipeline (R14-proven on Wo/FF2:
//         -9.6us combined). BK=32 lets the big QKV/FF1 tiles double-buffer
//         within the LDS residency budget (24/32 KB -> 2 blocks/CU) without
//         the R13 tile-shrink traffic penalty.
// PIPE=0: R12-proven 2-barrier loop (kept for fallback).
// EPI: 0 = bf16 out (+bias); 1 = f32 out (+bias+R residual); 2 = bf16 gelu;
//      3 = bf16 out (+bias), permuted store qkv[b][head][type][e][16].
// ---------------------------------------------------------------------------
template<int BM, int BN, int BK, int EPI, int PIPE>
__global__ __launch_bounds__(256) void mm_k(
    const bf16u* __restrict__ A, const bf16u* __restrict__ Wt,
    const float* __restrict__ bias, const float* __restrict__ R,
    void* __restrict__ Cout, int M, int N, int K)
{
  constexpr int WM = BM / 2, WN = BN / 2;
  constexpr int MT = WM / 16, NT = WN / 16;
  constexpr int PA = BM * BK / 2048, PB = BN * BK / 2048;
  constexpr int LBM = (BM == 128 ? 7 : 6), LBN = (BN == 128 ? 7 : 6);
  constexpr int SS = BK / 32;          // k=32 sub-steps per K-step
  constexpr int NBUF = PIPE ? 2 : 1;
  __shared__ bf16u As[NBUF][BM * BK];
  __shared__ bf16u Bs[NBUF][BN * BK];

  const int t = threadIdx.x;
  const int l15 = t & 15, quad = (t >> 4) & 3;
  const int w = t >> 6, wm = w >> 1, wn = w & 1;
  const int m0 = blockIdx.x * BM, n0 = blockIdx.y * BN;

  f32x4 acc[MT][NT];
  const f32x4 z4 = {0.f, 0.f, 0.f, 0.f};
#pragma unroll
  for (int i = 0; i < MT; ++i)
#pragma unroll
    for (int j = 0; j < NT; ++j) acc[i][j] = z4;

  if (PIPE) {
    const int NK = K / BK;
    // prologue: stage k-step 0 into buffer 0
#pragma unroll
    for (int p = 0; p < PA; ++p) {
      int g = p * 256 + t;
      int m = g & (BM - 1), c = g >> LBM;
      GLOAD_LDS16(A + (size_t)(m0 + m) * K + c * 8, &As[0][g * 8]);
    }
#pragma unroll
    for (int p = 0; p < PB; ++p) {
      int g = p * 256 + t;
      int n = g & (BN - 1), c = g >> LBN;
      GLOAD_LDS16(Wt + (size_t)(n0 + n) * K + c * 8, &Bs[0][g * 8]);
    }
    __syncthreads();

    for (int ki = 0; ki < NK; ++ki) {
      const int cur = ki & 1;
      if (ki + 1 < NK) {
        const int k0 = (ki + 1) * BK;
#pragma unroll
        for (int p = 0; p < PA; ++p) {
          int g = p * 256 + t;
          int m = g & (BM - 1), c = g >> LBM;
          GLOAD_LDS16(A + (size_t)(m0 + m) * K + k0 + c * 8,
                      &As[(cur ^ 1) & (NBUF - 1)][g * 8]);
        }
#pragma unroll
        for (int p = 0; p < PB; ++p) {
          int g = p * 256 + t;
          int n = g & (BN - 1), c = g >> LBN;
          GLOAD_LDS16(Wt + (size_t)(n0 + n) * K + k0 + c * 8,
                      &Bs[(cur ^ 1) & (NBUF - 1)][g * 8]);
        }
      }
#pragma unroll
      for (int s = 0; s < SS; ++s) {
        short8 af[MT], bfr[NT];
#pragma unroll
        for (int mt = 0; mt < MT; ++mt)
          af[mt] = *(const short8*)(&As[cur & (NBUF - 1)]
              [((s * 4 + quad) * BM + wm * WM + mt * 16 + l15) * 8]);
#pragma unroll
        for (int nt = 0; nt < NT; ++nt)
          bfr[nt] = *(const short8*)(&Bs[cur & (NBUF - 1)]
              [((s * 4 + quad) * BN + wn * WN + nt * 16 + l15) * 8]);
#pragma unroll
        for (int mt = 0; mt < MT; ++mt)
#pragma unroll
          for (int nt = 0; nt < NT; ++nt)
            acc[mt][nt] = __builtin_amdgcn_mfma_f32_16x16x32_bf16(
                af[mt], bfr[nt], acc[mt][nt], 0, 0, 0);
      }
      __syncthreads();
    }
  } else {
    for (int k0 = 0; k0 < K; k0 += BK) {
      __syncthreads();
#pragma unroll
      for (int p = 0; p < PA; ++p) {
        int g = p * 256 + t;
        int m = g & (BM - 1), c = g >> LBM;
        GLOAD_LDS16(A + (size_t)(m0 + m) * K + k0 + c * 8, &As[0][g * 8]);
      }
#pragma unroll
      for (int p = 0; p < PB; ++p) {
        int g = p * 256 + t;
        int n = g & (BN - 1), c = g >> LBN;
        GLOAD_LDS16(Wt + (size_t)(n0 + n) * K + k0 + c * 8, &Bs[0][g * 8]);
      }
      __syncthreads();
#pragma unroll
      for (int s = 0; s < SS; ++s) {
        short8 af[MT], bfr[NT];
#pragma unroll
        for (int mt = 0; mt < MT; ++mt)
          af[mt] = *(const short8*)(&As[0][((s * 4 + quad) * BM + wm * WM + mt * 16 + l15) * 8]);
#pragma unroll
        for (int nt = 0; nt < NT; ++nt)
          bfr[nt] = *(const short8*)(&Bs[0][((s * 4 + quad) * BN + wn * WN + nt * 16 + l15) * 8]);
#pragma unroll
        for (int mt = 0; mt < MT; ++mt)
#pragma unroll
          for (int nt = 0; nt < NT; ++nt)
            acc[mt][nt] = __builtin_amdgcn_mfma_f32_16x16x32_bf16(
                af[mt], bfr[nt], acc[mt][nt], 0, 0, 0);
      }
    }
  }

#pragma unroll
  for (int mt = 0; mt < MT; ++mt) {
#pragma unroll
    for (int nt = 0; nt < NT; ++nt) {
      int col = n0 + wn * WN + nt * 16 + l15;
      float bia = bias[col];
#pragma unroll
      for (int r = 0; r < 4; ++r) {
        int row = m0 + wm * WM + mt * 16 + quad * 4 + r;
        float v = acc[mt][nt][r] + bia;
        if (EPI == 3) {
          size_t pidx = ((((size_t)(row >> 10) * 16 + ((col >> 4) & 15)) * 3 +
                          (col >> 8)) * E_ + (row & 1023)) * 16 + (col & 15);
          ((bf16u*)Cout)[pidx] = f2bf(v);
        } else {
          size_t idx = (size_t)row * N + col;
          if (EPI == 1)      { ((float*)Cout)[idx] = v + R[idx]; }
          else if (EPI == 2) { ((bf16u*)Cout)[idx] = f2bf(gelu_exact(v)); }
          else               { ((bf16u*)Cout)[idx] = f2bf(v); }
        }
      }
    }
  }
}

// ---------------------------------------------------------------------------
// Fused prep: weight transposes + bias concat + x conversion, 1 launch.
// ---------------------------------------------------------------------------
__global__ __launch_bounds__(256) void prep_k(
    const float* __restrict__ Wq, const float* __restrict__ Wk,
    const float* __restrict__ Wv, const float* __restrict__ Wo,
    const float* __restrict__ Wf1, const float* __restrict__ Wf2,
    bf16u* __restrict__ Wqkvt, bf16u* __restrict__ Wot,
    bf16u* __restrict__ Wf1t, bf16u* __restrict__ Wf2t,
    const float* __restrict__ bq, const float* __restrict__ bk,
    const float* __restrict__ bv, float* __restrict__ bqkv,
    const float* __restrict__ X, bf16u* __restrict__ Xb)
{
  __shared__ float tile[32][33];
  const int gid = blockIdx.x;
  const int t = threadIdx.x;

  if (gid < 768) {
    const float* src; bf16u* dst; int K, N, bx, by;
    if (gid < 256) {
      const int z = gid >> 6, r = gid & 63;
      src = (z == 0) ? Wq : (z == 1) ? Wk : (z == 2) ? Wv : Wo;
      dst = (z == 0) ? Wqkvt : (z == 1) ? Wqkvt + 65536
          : (z == 2) ? Wqkvt + 131072 : Wot;
      K = 256; N = 256; bx = r & 7; by = r >> 3;
    } else if (gid < 512) {
      const int r = gid - 256;
      src = Wf1; dst = Wf1t; K = 256; N = 1024; bx = r & 7; by = r >> 3;
    } else {
      const int r = gid - 512;
      src = Wf2; dst = Wf2t; K = 1024; N = 256; bx = r & 31; by = r >> 5;
    }
    const int tx = t & 31, ty = t >> 5;
    const int kb = bx * 32, nb = by * 32;
#pragma unroll
    for (int r = 0; r < 4; ++r)
      tile[ty + 8 * r][tx] = src[(size_t)(kb + ty + 8 * r) * N + nb + tx];
    __syncthreads();
#pragma unroll
    for (int r = 0; r < 4; ++r)
      dst[(size_t)(nb + ty + 8 * r) * K + kb + tx] = f2bf(tile[tx][ty + 8 * r]);
  } else if (gid < 771) {
    int i = (gid - 768) * 256 + t;
    bqkv[i] = (i < 256) ? bq[i] : (i < 512) ? bk[i - 256] : bv[i - 512];
  } else {
    int i = (gid - 771) * 256 + t;
    float4 a = ((const float4*)X)[i * 2];
    float4 b = ((const float4*)X)[i * 2 + 1];
    uint4 o;
    o.x = f2bf(a.x) | ((unsigned)f2bf(a.y) << 16);
    o.y = f2bf(a.z) | ((unsigned)f2bf(a.w) << 16);
    o.z = f2bf(b.x) | ((unsigned)f2bf(b.y) << 16);
    o.w = f2bf(b.z) | ((unsigned)f2bf(b.w) << 16);
    ((uint4*)Xb)[i] = o;
  }
}

// ---------------------------------------------------------------------------
// MFMA flash attention — R12 best-measured version, byte-identical
// (54-63 us band across runs: R9 coalesced-qkv pipeline + setprio T5).
// ---------------------------------------------------------------------------
__global__ __launch_bounds__(256) void attn_k(
    const bf16u* __restrict__ qkv, const int* __restrict__ sb,
    const unsigned char* __restrict__ mask, const float* __restrict__ be,
    bf16u* __restrict__ O)
{
  __shared__ bf16u Kl[2][2][64][40];     // [buf][hp][key][d0-15,mask@16,0@17-31,pad]
  __shared__ bf16u Vt[2][2][2][16][40];  // [buf][hp][s2][d][32 permuted slots+pad]
  __shared__ float emb2[6][2];           // [s][hp] pre-scaled by log2e

  const int t    = threadIdx.x;
  const int b    = blockIdx.z;
  const int hg   = blockIdx.y;          // head pair 0..7
  const int w    = t >> 6;
  const int lane = t & 63;
  const int l15  = lane & 15;
  const int quad = lane >> 4;
  const int q0w  = blockIdx.x * 64 + w * 16;
  const float C2 = 0.36067376022224085f;   // 0.25 * log2(e)

  if (t < 12) emb2[t >> 1][t & 1] = be[(t >> 1) * 16 + hg * 2 + (t & 1)] * 1.44269504088896f;

  {  // zero both Kl buffers: cols 17..31 must stay 0 for the padded MFMA
    float4 z = {0.f, 0.f, 0.f, 0.f};
    float4* kp = (float4*)&Kl[0][0][0][0];
    for (int i = t; i < 1280; i += 256) kp[i] = z;
  }

  // Q B-frag: lane l15 = q, elems = d (quad*8+j); quads 2,3 zero-pad except
  // d=16 (quad2,j0) = 1.0 for the mask-inject trick.
  short8 qf[2];
#pragma unroll
  for (int hp = 0; hp < 2; ++hp) {
    uint4 v = {0u, 0u, 0u, 0u};
    if (quad < 2)
      v = *(const uint4*)(qkv +
          ((((size_t)b * 16 + hg * 2 + hp) * 3 + 0) * E_ + q0w + l15) * 16 + quad * 8);
    else if (quad == 2)
      v.x = 0x3F80u;  // bf16 1.0 (mask-inject slot d=16)
    union { uint4 u; short8 s; } c; c.u = v;
    qf[hp] = c.s;
  }

  // staging roles
  const int s_hp   = t >> 7;         // K/V: which head
  const int s_key  = (t >> 1) & 63;  // K: key
  const int s_half = t & 1;          // K: d-half
  const int vu     = t & 127;
  const int vz     = vu >> 2;        // key pair (2vz, 2vz+1)
  const int vh     = (vu >> 1) & 1;
  const int vjh    = vu & 1;
  const int vs2    = vz >> 4;
  const int vrow0  = vh * 8 + vjh * 4;
  const int vc     = ((vz >> 1) & 3) * 8 + ((vz >> 3) & 1) * 4 + (vz & 1) * 2;

  const bf16u* kbase = qkv + (((size_t)b * 16 + hg * 2 + s_hp) * 3 + 1) * E_ * 16 + s_half * 8;
  const bf16u* vbase = qkv + (((size_t)b * 16 + hg * 2 + s_hp) * 3 + 2) * E_ * 16 + vrow0;
  const int* sbp = sb + ((size_t)(b * E_) + q0w + l15) * E_;

  f32x4 accO[2];
  const f32x4 z4 = {0.f, 0.f, 0.f, 0.f};
  accO[0] = z4; accO[1] = z4;
  float lsum[2] = {0.f, 0.f};

  // ---- prologue: issue chunk-0 loads (latency overlaps zero-fill+barrier)
  uint4 kA;
  uint2 va, vb;
  unsigned mA;
  int sraw[2][2][4];
  {
    kA = *(const uint4*)(kbase + (size_t)s_key * 16);
    const bf16u* p0 = vbase + (size_t)(2 * vz) * 16;
    va = *(const uint2*)p0;
    vb = *(const uint2*)(p0 + 16);
    mA = mask[b * E_ + s_key];
#pragma unroll
    for (int s2 = 0; s2 < 2; ++s2)
#pragma unroll
      for (int kb2 = 0; kb2 < 2; ++kb2)
        *(int4*)&sraw[s2][kb2][0] =
            *(const int4*)(sbp + s2 * 32 + kb2 * 16 + quad * 4);
  }
  __syncthreads();   // zero-fill + emb2 visible before first staging write

#pragma unroll 2
  for (int i = 0; i < 16; ++i) {
    const int cur = i & 1;

    // ---- stage chunk i from regs -> LDS[cur]
    *(uint4*)&Kl[cur][s_hp][s_key][s_half * 8] = kA;
    {
      union { uint2 u; bf16u e[4]; } a, c; a.u = va; c.u = vb;
#pragma unroll
      for (int j = 0; j < 4; ++j)
        *(unsigned*)&Vt[cur][s_hp][vs2][vrow0 + j][vc] =
            (unsigned)a.e[j] | ((unsigned)c.e[j] << 16);
    }
    if (s_half == 0)
      Kl[cur][s_hp][s_key][16] = mA ? (bf16u)0xCF6E : (bf16u)0;

    __syncthreads();   // chunk i visible; buf^1 free (all waves past compute i-1)

    // ---- issue chunk i+1 loads: land during compute i (hidden latency)
    int srn[2][2][4];
    if (i < 15) {
      const int kn = (i + 1) * 64;
      kA = *(const uint4*)(kbase + (size_t)(kn + s_key) * 16);
      const bf16u* p0 = vbase + (size_t)(kn + 2 * vz) * 16;
      va = *(const uint2*)p0;
      vb = *(const uint2*)(p0 + 16);
      mA = mask[b * E_ + kn + s_key];
#pragma unroll
      for (int s2 = 0; s2 < 2; ++s2)
#pragma unroll
        for (int kb2 = 0; kb2 < 2; ++kb2)
          *(int4*)&srn[s2][kb2][0] =
              *(const int4*)(sbp + kn + s2 * 32 + kb2 * 16 + quad * 4);
    }

    // ---- compute chunk i (verbatim R3/R4 math, reading buf[cur])
    __builtin_amdgcn_s_setprio(1);
#pragma unroll
    for (int s2 = 0; s2 < 2; ++s2) {
      short8 k00 = *(const short8*)&Kl[cur][0][s2 * 32 + l15][quad * 8];
      short8 k01 = *(const short8*)&Kl[cur][0][s2 * 32 + 16 + l15][quad * 8];
      short8 k10 = *(const short8*)&Kl[cur][1][s2 * 32 + l15][quad * 8];
      short8 k11 = *(const short8*)&Kl[cur][1][s2 * 32 + 16 + l15][quad * 8];
      // swapped: C[key (quad*4+r)][q (l15)]
      f32x4 sc00 = __builtin_amdgcn_mfma_f32_16x16x32_bf16(k00, qf[0], z4, 0, 0, 0);
      f32x4 sc01 = __builtin_amdgcn_mfma_f32_16x16x32_bf16(k01, qf[0], z4, 0, 0, 0);
      f32x4 sc10 = __builtin_amdgcn_mfma_f32_16x16x32_bf16(k10, qf[1], z4, 0, 0, 0);
      f32x4 sc11 = __builtin_amdgcn_mfma_f32_16x16x32_bf16(k11, qf[1], z4, 0, 0, 0);

      unsigned pk0[4], pk1[4];
#pragma unroll
      for (int r = 0; r < 4; ++r) {
        float2 w0 = *(const float2*)&emb2[sraw[s2][0][r]][0];
        float2 w1 = *(const float2*)&emb2[sraw[s2][1][r]][0];
        float p00 = __builtin_amdgcn_exp2f(fmaf(sc00[r], C2, w0.x));  // hp0 kb0
        float p01 = __builtin_amdgcn_exp2f(fmaf(sc01[r], C2, w1.x));  // hp0 kb1
        float p10 = __builtin_amdgcn_exp2f(fmaf(sc10[r], C2, w0.y));  // hp1 kb0
        float p11 = __builtin_amdgcn_exp2f(fmaf(sc11[r], C2, w1.y));  // hp1 kb1
        unsigned u00 = __float_as_uint(p00), u01 = __float_as_uint(p01);
        unsigned u10 = __float_as_uint(p10), u11 = __float_as_uint(p11);
        lsum[0] += __uint_as_float(u00 & 0xffff0000u) + __uint_as_float(u01 & 0xffff0000u);
        lsum[1] += __uint_as_float(u10 & 0xffff0000u) + __uint_as_float(u11 & 0xffff0000u);
        if ((r & 1) == 0) {
          pk0[r >> 1]       = u00 >> 16;
          pk0[2 + (r >> 1)] = u01 >> 16;
          pk1[r >> 1]       = u10 >> 16;
          pk1[2 + (r >> 1)] = u11 >> 16;
        } else {
          pk0[r >> 1]       |= u00 & 0xffff0000u;
          pk0[2 + (r >> 1)] |= u01 & 0xffff0000u;
          pk1[r >> 1]       |= u10 & 0xffff0000u;
          pk1[2 + (r >> 1)] |= u11 & 0xffff0000u;
        }
      }
      union { unsigned u[4]; short8 s; } a0, a1;
      a0.u[0] = pk0[0]; a0.u[1] = pk0[1]; a0.u[2] = pk0[2]; a0.u[3] = pk0[3];
      a1.u[0] = pk1[0]; a1.u[1] = pk1[1]; a1.u[2] = pk1[2]; a1.u[3] = pk1[3];

      short8 vf0 = *(const short8*)&Vt[cur][0][s2][l15][quad * 8];
      short8 vf1 = *(const short8*)&Vt[cur][1][s2][l15][quad * 8];
      accO[0] = __builtin_amdgcn_mfma_f32_16x16x32_bf16(a0.s, vf0, accO[0], 0, 0, 0);
      accO[1] = __builtin_amdgcn_mfma_f32_16x16x32_bf16(a1.s, vf1, accO[1], 0, 0, 0);
    }
    __builtin_amdgcn_s_setprio(0);

    // ---- rotate sb regs
    if (i < 15) {
#pragma unroll
      for (int s2 = 0; s2 < 2; ++s2)
#pragma unroll
        for (int kb2 = 0; kb2 < 2; ++kb2)
#pragma unroll
          for (int r = 0; r < 4; ++r)
            sraw[s2][kb2][r] = srn[s2][kb2][r];
    }
  }

  // lsum per-q on l15 (quads hold disjoint key subsets): reduce, then
  // redistribute to C-layout rows (q = quad*4 + r).
#pragma unroll
  for (int hp = 0; hp < 2; ++hp) {
    lsum[hp] += __shfl_xor(lsum[hp], 16, 64);
    lsum[hp] += __shfl_xor(lsum[hp], 32, 64);
  }
#pragma unroll
  for (int hp = 0; hp < 2; ++hp) {
#pragma unroll
    for (int r = 0; r < 4; ++r) {
      float lq = __shfl(lsum[hp], quad * 4 + r, 64);
      float o = accO[hp][r] / lq;
      O[((size_t)(b * E_) + q0w + quad * 4 + r) * 256 + (hg * 2 + hp) * 16 + l15] = f2bf(o);
    }
  }
}

// ---------------------------------------------------------------------------
// LayerNorm, one wave per row of 256. DUAL: also write bf16 copy.
// ---------------------------------------------------------------------------
template<int DUAL>
__global__ __launch_bounds__(256) void ln_k(
    const float* __restrict__ X, const float* __restrict__ g,
    const float* __restrict__ bta, float* __restrict__ Y, bf16u* __restrict__ Yb)
{
  const int row  = blockIdx.x * 4 + (threadIdx.x >> 6);
  const int lane = threadIdx.x & 63;
  float4 v = *(const float4*)(X + (size_t)row * D_ + lane * 4);
  float s  = v.x + v.y + v.z + v.w;
  float ss = v.x * v.x + v.y * v.y + v.z * v.z + v.w * v.w;
#pragma unroll
  for (int off = 32; off; off >>= 1) {
    s  += __shfl_xor(s, off, 64);
    ss += __shfl_xor(ss, off, 64);
  }
  float mu  = s * (1.f / 256.f);
  float var = ss * (1.f / 256.f) - mu * mu;
  float rs  = 1.f / sqrtf(var + 1e-5f);
  float4 gv = *(const float4*)(g + lane * 4);
  float4 bv = *(const float4*)(bta + lane * 4);
  float4 o;
  o.x = (v.x - mu) * rs * gv.x + bv.x;
  o.y = (v.y - mu) * rs * gv.y + bv.y;
  o.z = (v.z - mu) * rs * gv.z + bv.z;
  o.w = (v.w - mu) * rs * gv.w + bv.w;
  *(float4*)(Y + (size_t)row * D_ + lane * 4) = o;
  if (DUAL) {
    uint2 p;
    p.x = f2bf(o.x) | ((unsigned)f2bf(o.y) << 16);
    p.y = f2bf(o.z) | ((unsigned)f2bf(o.w) << 16);
    *(uint2*)(Yb + (size_t)row * D_ + lane * 4) = p;
  }
}

// ---------------------------------------------------------------------------
extern "C" void kernel_launch(void* const* d_in, const int* in_sizes, int n_in,
                              void* d_out, int out_size, void* d_ws, size_t ws_size,
                              hipStream_t stream) {
  const float* x   = (const float*)d_in[0];
  const int*   sb  = (const int*)d_in[1];
  const unsigned char* mask = (const unsigned char*)d_in[2];
  const float* Wq  = (const float*)d_in[3];
  const float* bq  = (const float*)d_in[4];
  const float* Wk  = (const float*)d_in[5];
  const float* bk  = (const float*)d_in[6];
  const float* Wv  = (const float*)d_in[7];
  const float* bv  = (const float*)d_in[8];
  const float* Wo  = (const float*)d_in[9];
  const float* bo  = (const float*)d_in[10];
  const float* be  = (const float*)d_in[11];
  const float* g1  = (const float*)d_in[12];
  const float* b1  = (const float*)d_in[13];
  const float* Wf1 = (const float*)d_in[14];
  const float* bf1 = (const float*)d_in[15];
  const float* Wf2 = (const float*)d_in[16];
  const float* bf2 = (const float*)d_in[17];
  const float* g2  = (const float*)d_in[18];
  const float* b2  = (const float*)d_in[19];
  float* out = (float*)d_out;

  char* ws = (char*)d_ws;
  bf16u* Wqkvt = (bf16u*)(ws + 0);          // 768*256*2
  bf16u* Wot   = (bf16u*)(ws + 393216);     // 256*256*2
  bf16u* Wf1t  = (bf16u*)(ws + 524288);     // 1024*256*2
  bf16u* Wf2t  = (bf16u*)(ws + 1048576);    // 256*1024*2
  float* bqkv  = (float*)(ws + 1572864);    // 768*4
  bf16u* xb    = (bf16u*)(ws + 2097152);    // 4 MB   [dead after qkv gemm]
  bf16u* qkv   = (bf16u*)(ws + 6291456);    // 12.6 MB [dead after attn]
  bf16u* att   = (bf16u*)(ws + 18874368);   // 4 MB
  float* t1    = (float*)(ws + 23068672);   // 8 MB   [dead after ln1]
  float* x1    = (float*)(ws + 31457280);   // 8 MB
  bf16u* x1b   = (bf16u*)(ws + 39845888);   // 4 MB
  bf16u* ffh   = (bf16u*)(ws + 2097152);    // 16 MB, reuses xb+qkv
  float* t2    = (float*)(ws + 18874368);   // 8 MB, reuses att+t1

  dim3 blk(256);

  prep_k<<<1795, blk, 0, stream>>>(Wq, Wk, Wv, Wo, Wf1, Wf2,
                                   Wqkvt, Wot, Wf1t, Wf2t,
                                   bq, bk, bv, bqkv, x, xb);

  // QKV projection -> qkv bf16, permuted layout
  // (pipelined, big 64x128 tiles kept via BK=32: dbuf LDS 24KB -> 2/CU)
  mm_k<64, 128, 32, 3, 1><<<dim3(128, 6), blk, 0, stream>>>(
      xb, Wqkvt, bqkv, nullptr, qkv, M_, 768, 256);
  // MFMA flash attention -> att bf16 (R12 pipeline + setprio, unchanged)
  attn_k<<<dim3(16, 8, 8), blk, 0, stream>>>(qkv, sb, mask, be, att);

  // out-proj + residual -> t1 fp32 (pipelined 64x64 BK=64, R14-proven)
  mm_k<64, 64, 64, 1, 1><<<dim3(128, 4), blk, 0, stream>>>(
      att, Wot, bo, x, t1, M_, 256, 256);
  ln_k<1><<<M_ / 4, blk, 0, stream>>>(t1, g1, b1, x1, x1b);

  // FFN: FF1 pipelined at full 128x128 via BK=32 (dbuf 32KB -> 2/CU);
  //      FF2 pipelined 64x64 BK=64 (R14-proven)
  mm_k<128, 128, 32, 2, 1><<<dim3(64, 8), blk, 0, stream>>>(
      x1b, Wf1t, bf1, nullptr, ffh, M_, 1024, 256);
  mm_k<64, 64, 64, 1, 1><<<dim3(128, 4), blk, 0, stream>>>(
      ffh, Wf2t, bf2, x1, t2, M_, 256, 1024);
  ln_k<0><<<M_ / 4, blk, 0, stream>>>(t2, g2, b2, out, nullptr);
}